// Round 1
// baseline (321.791 us; speedup 1.0000x reference)
//
#include <hip/hip_runtime.h>

#define TOKENS 2048
#define HIDDEN 1024
#define NEXP   8
#define INTER  2816
#define N1     5632   // 2*INTER
#define ROWCAP 5120   // 4096 pairs + 8*128 padding worst case

typedef __attribute__((ext_vector_type(8))) short short8;   // 8 bf16 = 4 VGPR (MFMA A/B frag)
typedef __attribute__((ext_vector_type(4))) float f32x4;    // MFMA C/D frag

typedef unsigned int __attribute__((address_space(1))) as1_uint;
typedef unsigned int __attribute__((address_space(3))) as3_uint;

__device__ __forceinline__ void gload16(const void* g, void* l) {
  // async global->LDS, 16B/lane, LDS dest = wave-uniform base + lane*16
  __builtin_amdgcn_global_load_lds((const as1_uint*)g, (as3_uint*)l, 16, 0, 0);
}

__device__ __forceinline__ unsigned short f2bf(float f) {  // RNE f32->bf16
  unsigned u = __float_as_uint(f);
  u += 0x7fff + ((u >> 16) & 1);
  return (unsigned short)(u >> 16);
}
__device__ __forceinline__ float bf2f(unsigned short h) {
  return __uint_as_float(((unsigned)h) << 16);
}

// ---------------- routing: softmax->top2->renorm == sigmoid(l0-l1) ----------------
__global__ void k_routing(const float* __restrict__ gate, int* __restrict__ ctrl,
                          int* __restrict__ tkid, float* __restrict__ tkw) {
  int t = blockIdx.x * blockDim.x + threadIdx.x;
  if (t >= TOKENS) return;
  float l[8];
#pragma unroll
  for (int i = 0; i < 8; i++) l[i] = gate[t * 8 + i];
  int i0 = 0; float m0 = l[0];
#pragma unroll
  for (int i = 1; i < 8; i++) if (l[i] > m0) { m0 = l[i]; i0 = i; }
  int i1 = -1; float m1 = -3.4e38f;
#pragma unroll
  for (int i = 0; i < 8; i++) if (i != i0 && l[i] > m1) { m1 = l[i]; i1 = i; }
  float e  = __expf(m1 - m0);          // <= 1, stable
  float w0 = 1.f / (1.f + e);
  float w1 = e / (1.f + e);
  tkid[2 * t] = i0; tkid[2 * t + 1] = i1;
  tkw[2 * t] = w0;  tkw[2 * t + 1] = w1;
  atomicAdd(&ctrl[i0], 1);
  atomicAdd(&ctrl[i1], 1);
}

// ctrl layout (ints): [0..7]=cnt  [8..15]=cursor  [16..23]=base (128-aligned prefix)
__global__ void k_base(int* ctrl) {
  if (threadIdx.x == 0) {
    int a = 0;
    for (int e = 0; e < 8; e++) { ctrl[16 + e] = a; a += ((ctrl[e] + 127) >> 7) << 7; }
  }
}

__global__ void k_fill(int* __restrict__ ctrl, const int* __restrict__ tkid,
                       const float* __restrict__ tkw, int* __restrict__ rtok,
                       float* __restrict__ rwgt) {
  int t = blockIdx.x * blockDim.x + threadIdx.x;
  if (t >= TOKENS) return;
#pragma unroll
  for (int k = 0; k < 2; k++) {
    int e = tkid[2 * t + k];
    int pos = atomicAdd(&ctrl[8 + e], 1);
    int row = ctrl[16 + e] + pos;
    rtok[row] = t; rwgt[row] = tkw[2 * t + k];
  }
}

// gather x rows (f32) -> bf16 A matrix ordered by expert segment; zero padded rows
__global__ void k_gather(const float* __restrict__ x, const int* __restrict__ ctrl,
                         const int* __restrict__ rtok, unsigned short* __restrict__ Abf) {
  int row = blockIdx.x;
  int e = -1, local = 0;
  for (int i = 0; i < 8; i++) {
    int b = ctrl[16 + i], p = ((ctrl[i] + 127) >> 7) << 7;
    if (row >= b && row < b + p) { e = i; local = row - b; break; }
  }
  if (e < 0) return;
  int tid = threadIdx.x;
  unsigned short* dst = Abf + (size_t)row * HIDDEN;
  if (local < ctrl[e]) {
    int t = rtok[row];
    float4 v = ((const float4*)(x + (size_t)t * HIDDEN))[tid];
    ushort4 o; o.x = f2bf(v.x); o.y = f2bf(v.y); o.z = f2bf(v.z); o.w = f2bf(v.w);
    ((ushort4*)dst)[tid] = o;
  } else {
    ushort4 z; z.x = 0; z.y = 0; z.z = 0; z.w = 0;
    ((ushort4*)dst)[tid] = z;
  }
}

// ---------------- GEMM1: h = A * w1[e]^T  (128 rows x [64 gate|64 up] cols), fused SiLU ----
// LDS tiles [128][64] bf16, XOR-swizzle byte^=((row&7)<<4) on 16B blocks (G4).
__global__ __launch_bounds__(256, 2) void k_gemm1(const float* __restrict__ w1,
    const unsigned short* __restrict__ Abf, unsigned short* __restrict__ act,
    const int* __restrict__ ctrl) {
  union __align__(16) LdsU {
    struct { unsigned char A[16384]; unsigned char B[16384]; } st;
    unsigned short hb[128 * 132];
  };
  __shared__ LdsU lds;
  int mt = blockIdx.y;
  int e = -1, ml = 0;
  { int a0 = 0;
    for (int i = 0; i < 8; i++) { int pt = (ctrl[i] + 127) >> 7;
      if (mt < a0 + pt) { e = i; ml = mt - a0; break; } a0 += pt; } }
  if (e < 0) return;
  int nt = blockIdx.x;                               // 0..43 : inter cols [nt*64, nt*64+64)
  int tid = threadIdx.x, lane = tid & 63, wid = tid >> 6, wr = wid >> 1, wc = wid & 1;
  int rbase = ctrl[16 + e] + ml * 128;
  const unsigned char* Ab = (const unsigned char*)(Abf + (size_t)rbase * HIDDEN);
  const float* Bb = w1 + (size_t)e * N1 * HIDDEN;

  f32x4 acc[4][4];
  f32x4 zero = {0.f, 0.f, 0.f, 0.f};
#pragma unroll
  for (int i = 0; i < 4; i++)
#pragma unroll
    for (int j = 0; j < 4; j++) acc[i][j] = zero;

  for (int kk = 0; kk < HIDDEN / 64; ++kk) {
    // A: global_load_lds, pre-swizzled source so linear LDS == swizzled layout
#pragma unroll
    for (int i = 0; i < 4; i++) {
      int g = wid * 4 + i;                           // 8-row group
      int row = g * 8 + (lane >> 3);
      gload16(Ab + (size_t)row * (HIDDEN * 2) + kk * 128 + (((lane & 7) ^ (lane >> 3)) << 4),
              &lds.st.A[g * 1024]);
    }
    // B: w1 f32 -> bf16 -> LDS (rows 0..63 = gate nt*64+r, 64..127 = up 2816+nt*64+r)
#pragma unroll
    for (int i = 0; i < 8; i++) {
      int f = i * 256 + tid;
      int row = f >> 4, kq = f & 15;
      int grow = (row < 64) ? (nt * 64 + row) : (INTER + nt * 64 + (row - 64));
      float4 v = *(const float4*)(Bb + (size_t)grow * HIDDEN + kk * 64 + kq * 4);
      ushort4 o; o.x = f2bf(v.x); o.y = f2bf(v.y); o.z = f2bf(v.z); o.w = f2bf(v.w);
      *(ushort4*)&lds.st.B[row * 128 + ((kq * 8) ^ ((row & 7) << 4))] = o;
    }
    __syncthreads();
#pragma unroll
    for (int ks = 0; ks < 2; ++ks) {
      short8 a[4], b[4];
#pragma unroll
      for (int mi = 0; mi < 4; mi++) {
        int row = wr * 64 + mi * 16 + (lane & 15);
        int koff = ks * 64 + ((lane >> 4) << 4);
        a[mi] = *(const short8*)&lds.st.A[row * 128 + (koff ^ ((row & 7) << 4))];
      }
#pragma unroll
      for (int ni = 0; ni < 4; ni++) {
        int row = wc * 64 + ni * 16 + (lane & 15);
        int koff = ks * 64 + ((lane >> 4) << 4);
        b[ni] = *(const short8*)&lds.st.B[row * 128 + (koff ^ ((row & 7) << 4))];
      }
#pragma unroll
      for (int mi = 0; mi < 4; mi++)
#pragma unroll
        for (int ni = 0; ni < 4; ni++)
          acc[mi][ni] = __builtin_amdgcn_mfma_f32_16x16x32_bf16(a[mi], b[ni], acc[mi][ni], 0, 0, 0);
    }
    __syncthreads();
  }
  // epilogue: h -> LDS (bf16), then act = silu(gate)*up -> global
#pragma unroll
  for (int mi = 0; mi < 4; mi++)
#pragma unroll
    for (int ni = 0; ni < 4; ni++)
#pragma unroll
      for (int r = 0; r < 4; r++) {
        int row = wr * 64 + mi * 16 + ((lane >> 4) << 2) + r;   // C/D: row=(lane>>4)*4+reg
        int col = wc * 64 + ni * 16 + (lane & 15);              //      col=lane&15
        lds.hb[row * 132 + col] = f2bf(acc[mi][ni][r]);
      }
  __syncthreads();
  {
    int r = tid >> 1, ch = (tid & 1) * 32;
    unsigned short* orow = act + (size_t)(rbase + r) * INTER + nt * 64 + ch;
    const unsigned short* hrow = &lds.hb[r * 132];
#pragma unroll
    for (int j = 0; j < 32; j += 4) {
      ushort4 o;
#pragma unroll
      for (int q = 0; q < 4; q++) {
        float g = bf2f(hrow[ch + j + q]);
        float u = bf2f(hrow[64 + ch + j + q]);
        float s = g / (1.f + __expf(-g));
        ((unsigned short*)&o)[q] = f2bf(s * u);
      }
      *(ushort4*)(orow + j) = o;
    }
  }
}

// ---------------- GEMM2: out_rows = act * w2[e]^T, weighted atomic scatter ----------------
struct Lds2 { unsigned char A[16384]; unsigned char B[16384]; };

__global__ __launch_bounds__(256, 2) void k_gemm2(const float* __restrict__ w2,
    const unsigned short* __restrict__ act, float* __restrict__ out,
    const int* __restrict__ ctrl, const int* __restrict__ rtok,
    const float* __restrict__ rwgt) {
  __shared__ __align__(16) Lds2 lds;
  int mt = blockIdx.y;
  int e = -1, ml = 0;
  { int a0 = 0;
    for (int i = 0; i < 8; i++) { int pt = (ctrl[i] + 127) >> 7;
      if (mt < a0 + pt) { e = i; ml = mt - a0; break; } a0 += pt; } }
  if (e < 0) return;
  int nt = blockIdx.x;                               // 0..7 : out cols [nt*128, +128)
  int tid = threadIdx.x, lane = tid & 63, wid = tid >> 6, wr = wid >> 1, wc = wid & 1;
  int rbase = ctrl[16 + e] + ml * 128;
  const unsigned char* Ab = (const unsigned char*)(act + (size_t)rbase * INTER);
  const float* Bb = w2 + (size_t)e * HIDDEN * INTER + (size_t)(nt * 128) * INTER;

  f32x4 acc[4][4];
  f32x4 zero = {0.f, 0.f, 0.f, 0.f};
#pragma unroll
  for (int i = 0; i < 4; i++)
#pragma unroll
    for (int j = 0; j < 4; j++) acc[i][j] = zero;

  for (int kk = 0; kk < INTER / 64; ++kk) {
#pragma unroll
    for (int i = 0; i < 4; i++) {
      int g = wid * 4 + i;
      int row = g * 8 + (lane >> 3);
      gload16(Ab + (size_t)row * (INTER * 2) + kk * 128 + (((lane & 7) ^ (lane >> 3)) << 4),
              &lds.A[g * 1024]);
    }
#pragma unroll
    for (int i = 0; i < 8; i++) {
      int f = i * 256 + tid;
      int row = f >> 4, kq = f & 15;
      float4 v = *(const float4*)(Bb + (size_t)row * INTER + kk * 64 + kq * 4);
      ushort4 o; o.x = f2bf(v.x); o.y = f2bf(v.y); o.z = f2bf(v.z); o.w = f2bf(v.w);
      *(ushort4*)&lds.B[row * 128 + ((kq * 8) ^ ((row & 7) << 4))] = o;
    }
    __syncthreads();
#pragma unroll
    for (int ks = 0; ks < 2; ++ks) {
      short8 a[4], b[4];
#pragma unroll
      for (int mi = 0; mi < 4; mi++) {
        int row = wr * 64 + mi * 16 + (lane & 15);
        int koff = ks * 64 + ((lane >> 4) << 4);
        a[mi] = *(const short8*)&lds.A[row * 128 + (koff ^ ((row & 7) << 4))];
      }
#pragma unroll
      for (int ni = 0; ni < 4; ni++) {
        int row = wc * 64 + ni * 16 + (lane & 15);
        int koff = ks * 64 + ((lane >> 4) << 4);
        b[ni] = *(const short8*)&lds.B[row * 128 + (koff ^ ((row & 7) << 4))];
      }
#pragma unroll
      for (int mi = 0; mi < 4; mi++)
#pragma unroll
        for (int ni = 0; ni < 4; ni++)
          acc[mi][ni] = __builtin_amdgcn_mfma_f32_16x16x32_bf16(a[mi], b[ni], acc[mi][ni], 0, 0, 0);
    }
    __syncthreads();
  }
  // weighted scatter: each out element gets exactly 2 commutative fp32 atomic adds
  int cn = ctrl[e];
#pragma unroll
  for (int mi = 0; mi < 4; mi++)
#pragma unroll
    for (int ni = 0; ni < 4; ni++)
#pragma unroll
      for (int r = 0; r < 4; r++) {
        int rl = wr * 64 + mi * 16 + ((lane >> 4) << 2) + r;
        if (ml * 128 + rl < cn) {
          int rowg = rbase + rl;
          int t = rtok[rowg];
          float wgt = rwgt[rowg];
          int col = nt * 128 + wc * 64 + ni * 16 + (lane & 15);
          atomicAdd(out + (size_t)t * HIDDEN + col, wgt * acc[mi][ni][r]);
        }
      }
}

extern "C" void kernel_launch(void* const* d_in, const int* in_sizes, int n_in,
                              void* d_out, int out_size, void* d_ws, size_t ws_size,
                              hipStream_t stream) {
  const float* x      = (const float*)d_in[0];
  const float* gating = (const float*)d_in[1];
  const float* w1     = (const float*)d_in[2];
  const float* w2     = (const float*)d_in[3];
  float* out = (float*)d_out;
  char* ws = (char*)d_ws;

  // ws layout
  int*   ctrl = (int*)ws;                                   // cnt[8] cursor[8] base[8]
  int*   tkid = (int*)(ws + 1024);                          // 4096 ints
  float* tkw  = (float*)(ws + 17408);                       // 4096 floats
  int*   rtok = (int*)(ws + 33792);                         // 5120 ints
  float* rwgt = (float*)(ws + 54272);                       // 5120 floats
  unsigned short* Abf  = (unsigned short*)(ws + 131072);    // 5120*1024 bf16 (10.5MB)
  unsigned short* actb = (unsigned short*)(ws + 131072 + (size_t)ROWCAP * HIDDEN * 2); // 5120*2816 bf16 (28.8MB)

  hipMemsetAsync(d_out, 0, (size_t)TOKENS * HIDDEN * sizeof(float), stream);
  hipMemsetAsync(ws, 0, 1024, stream);

  k_routing<<<TOKENS / 256, 256, 0, stream>>>(gating, ctrl, tkid, tkw);
  k_base<<<1, 64, 0, stream>>>(ctrl);
  k_fill<<<TOKENS / 256, 256, 0, stream>>>(ctrl, tkid, tkw, rtok, rwgt);
  k_gather<<<ROWCAP, 256, 0, stream>>>(x, ctrl, rtok, Abf);
  k_gemm1<<<dim3(N1 / 128, 40), 256, 0, stream>>>(w1, Abf, actb, ctrl);
  k_gemm2<<<dim3(HIDDEN / 128, 40), 256, 0, stream>>>(w2, actb, out, ctrl, rtok, rwgt);
}

// Round 2
// 287.398 us; speedup vs baseline: 1.1197x; 1.1197x over previous
//
#include <hip/hip_runtime.h>

#define TOKENS 2048
#define HIDDEN 1024
#define NEXP   8
#define INTER  2816
#define N1     5632   // 2*INTER
#define ROWCAP 5120   // 4096 pairs + 8*128 padding worst case

typedef __attribute__((ext_vector_type(8))) short short8;   // 8 bf16 = 4 VGPR (MFMA A/B frag)
typedef __attribute__((ext_vector_type(4))) float f32x4;    // MFMA C/D frag

typedef unsigned int __attribute__((address_space(1))) as1_uint;
typedef unsigned int __attribute__((address_space(3))) as3_uint;

__device__ __forceinline__ void gload16(const void* g, void* l) {
  // async global->LDS, 16B/lane, LDS dest = wave-uniform base + lane*16
  __builtin_amdgcn_global_load_lds((const as1_uint*)g, (as3_uint*)l, 16, 0, 0);
}

__device__ __forceinline__ unsigned short f2bf(float f) {  // RNE f32->bf16
  unsigned u = __float_as_uint(f);
  u += 0x7fff + ((u >> 16) & 1);
  return (unsigned short)(u >> 16);
}
__device__ __forceinline__ float bf2f(unsigned short h) {
  return __uint_as_float(((unsigned)h) << 16);
}

// ---------------- weight f32 -> bf16 pre-convert (pure BW) ----------------
__global__ void k_conv(const float* __restrict__ src, unsigned short* __restrict__ dst, int n8) {
  int i = blockIdx.x * blockDim.x + threadIdx.x;
  int stride = gridDim.x * blockDim.x;
  for (; i < n8; i += stride) {
    float4 a = ((const float4*)src)[2 * i];
    float4 b = ((const float4*)src)[2 * i + 1];
    union { ushort us[8]; uint4 v; } o;
    o.us[0] = f2bf(a.x); o.us[1] = f2bf(a.y); o.us[2] = f2bf(a.z); o.us[3] = f2bf(a.w);
    o.us[4] = f2bf(b.x); o.us[5] = f2bf(b.y); o.us[6] = f2bf(b.z); o.us[7] = f2bf(b.w);
    ((uint4*)dst)[i] = o.v;
  }
}

// ---------------- routing: softmax->top2->renorm == sigmoid(l0-l1) ----------------
__global__ void k_routing(const float* __restrict__ gate, int* __restrict__ ctrl,
                          int* __restrict__ tkid, float* __restrict__ tkw) {
  int t = blockIdx.x * blockDim.x + threadIdx.x;
  if (t >= TOKENS) return;
  float l[8];
#pragma unroll
  for (int i = 0; i < 8; i++) l[i] = gate[t * 8 + i];
  int i0 = 0; float m0 = l[0];
#pragma unroll
  for (int i = 1; i < 8; i++) if (l[i] > m0) { m0 = l[i]; i0 = i; }
  int i1 = -1; float m1 = -3.4e38f;
#pragma unroll
  for (int i = 0; i < 8; i++) if (i != i0 && l[i] > m1) { m1 = l[i]; i1 = i; }
  float e  = __expf(m1 - m0);          // <= 1, stable
  float w0 = 1.f / (1.f + e);
  float w1 = e / (1.f + e);
  tkid[2 * t] = i0; tkid[2 * t + 1] = i1;
  tkw[2 * t] = w0;  tkw[2 * t + 1] = w1;
  atomicAdd(&ctrl[i0], 1);
  atomicAdd(&ctrl[i1], 1);
}

// ctrl layout (ints): [0..7]=cnt  [8..15]=cursor  [16..23]=base (128-aligned prefix)
__global__ void k_base(int* ctrl) {
  if (threadIdx.x == 0) {
    int a = 0;
    for (int e = 0; e < 8; e++) { ctrl[16 + e] = a; a += ((ctrl[e] + 127) >> 7) << 7; }
  }
}

__global__ void k_fill(int* __restrict__ ctrl, const int* __restrict__ tkid,
                       const float* __restrict__ tkw, int* __restrict__ rtok,
                       float* __restrict__ rwgt) {
  int t = blockIdx.x * blockDim.x + threadIdx.x;
  if (t >= TOKENS) return;
#pragma unroll
  for (int k = 0; k < 2; k++) {
    int e = tkid[2 * t + k];
    int pos = atomicAdd(&ctrl[8 + e], 1);
    int row = ctrl[16 + e] + pos;
    rtok[row] = t; rwgt[row] = tkw[2 * t + k];
  }
}

// gather x rows (f32) -> bf16 A matrix ordered by expert segment; zero padded rows
__global__ void k_gather(const float* __restrict__ x, const int* __restrict__ ctrl,
                         const int* __restrict__ rtok, unsigned short* __restrict__ Abf) {
  int row = blockIdx.x;
  int e = -1, local = 0;
  for (int i = 0; i < 8; i++) {
    int b = ctrl[16 + i], p = ((ctrl[i] + 127) >> 7) << 7;
    if (row >= b && row < b + p) { e = i; local = row - b; break; }
  }
  if (e < 0) return;
  int tid = threadIdx.x;
  unsigned short* dst = Abf + (size_t)row * HIDDEN;
  if (local < ctrl[e]) {
    int t = rtok[row];
    float4 v = ((const float4*)(x + (size_t)t * HIDDEN))[tid];
    ushort4 o; o.x = f2bf(v.x); o.y = f2bf(v.y); o.z = f2bf(v.z); o.w = f2bf(v.w);
    ((ushort4*)dst)[tid] = o;
  } else {
    ushort4 z; z.x = 0; z.y = 0; z.z = 0; z.w = 0;
    ((ushort4*)dst)[tid] = z;
  }
}

// expert/tile lookup shared by all GEMMs
__device__ __forceinline__ int tile_lookup(const int* ctrl, int mt, int* ml) {
  int a0 = 0;
  for (int i = 0; i < 8; i++) {
    int pt = (ctrl[i] + 127) >> 7;
    if (mt < a0 + pt) { *ml = mt - a0; return i; }
    a0 += pt;
  }
  return -1;
}

// ================= fast path: bf16 weights, both operands via global_load_lds ============
// LDS tiles [128][64] bf16, XOR-swizzle (row&7)<<4 on 16B blocks; linear dest via
// pre-swizzled global source (both-sides-or-neither rule).
__global__ __launch_bounds__(256, 4) void k_gemm1b(const unsigned short* __restrict__ w1b,
    const unsigned short* __restrict__ Abf, unsigned short* __restrict__ act,
    const int* __restrict__ ctrl) {
  union __align__(16) LdsU {
    struct { unsigned char A[16384]; unsigned char B[16384]; } st;
    unsigned short hb[128 * 132];
  };
  __shared__ LdsU lds;
  int mt = blockIdx.y, ml;
  int e = tile_lookup(ctrl, mt, &ml);
  if (e < 0) return;
  int nt = blockIdx.x;                               // 0..43 : inter cols [nt*64, nt*64+64)
  int tid = threadIdx.x, lane = tid & 63, wid = tid >> 6, wr = wid >> 1, wc = wid & 1;
  int rbase = ctrl[16 + e] + ml * 128;
  const unsigned char* Ab = (const unsigned char*)(Abf + (size_t)rbase * HIDDEN);
  const unsigned char* Bb = (const unsigned char*)(w1b + (size_t)e * N1 * HIDDEN);
  int swz = ((lane & 7) ^ (lane >> 3)) << 4;
  int l3 = lane >> 3;

  f32x4 acc[4][4];
  f32x4 zero = {0.f, 0.f, 0.f, 0.f};
#pragma unroll
  for (int i = 0; i < 4; i++)
#pragma unroll
    for (int j = 0; j < 4; j++) acc[i][j] = zero;

  for (int kk = 0; kk < HIDDEN / 64; ++kk) {
#pragma unroll
    for (int i = 0; i < 4; i++) {
      int g = wid * 4 + i;                           // 8-row group
      gload16(Ab + (size_t)(g * 8 + l3) * (HIDDEN * 2) + kk * 128 + swz, &lds.st.A[g * 1024]);
    }
#pragma unroll
    for (int i = 0; i < 4; i++) {
      int g = wid * 4 + i;
      int r0 = g * 8;
      int grow = (r0 < 64) ? (nt * 64 + r0 + l3) : (INTER + nt * 64 + r0 - 64 + l3);
      gload16(Bb + (size_t)grow * (HIDDEN * 2) + kk * 128 + swz, &lds.st.B[g * 1024]);
    }
    __syncthreads();
#pragma unroll
    for (int ks = 0; ks < 2; ++ks) {
      short8 a[4], b[4];
#pragma unroll
      for (int mi = 0; mi < 4; mi++) {
        int row = wr * 64 + mi * 16 + (lane & 15);
        int koff = ks * 64 + ((lane >> 4) << 4);
        a[mi] = *(const short8*)&lds.st.A[row * 128 + (koff ^ ((row & 7) << 4))];
      }
#pragma unroll
      for (int ni = 0; ni < 4; ni++) {
        int row = wc * 64 + ni * 16 + (lane & 15);
        int koff = ks * 64 + ((lane >> 4) << 4);
        b[ni] = *(const short8*)&lds.st.B[row * 128 + (koff ^ ((row & 7) << 4))];
      }
#pragma unroll
      for (int mi = 0; mi < 4; mi++)
#pragma unroll
        for (int ni = 0; ni < 4; ni++)
          acc[mi][ni] = __builtin_amdgcn_mfma_f32_16x16x32_bf16(a[mi], b[ni], acc[mi][ni], 0, 0, 0);
    }
    __syncthreads();
  }
  // epilogue: h -> LDS (bf16), then act = silu(gate)*up -> global
#pragma unroll
  for (int mi = 0; mi < 4; mi++)
#pragma unroll
    for (int ni = 0; ni < 4; ni++)
#pragma unroll
      for (int r = 0; r < 4; r++) {
        int row = wr * 64 + mi * 16 + ((lane >> 4) << 2) + r;   // C/D: row=(lane>>4)*4+reg
        int col = wc * 64 + ni * 16 + (lane & 15);              //      col=lane&15
        lds.hb[row * 132 + col] = f2bf(acc[mi][ni][r]);
      }
  __syncthreads();
  {
    int r = tid >> 1, ch = (tid & 1) * 32;
    unsigned short* orow = act + (size_t)(rbase + r) * INTER + nt * 64 + ch;
    const unsigned short* hrow = &lds.hb[r * 132];
#pragma unroll
    for (int j = 0; j < 32; j += 4) {
      ushort4 o;
#pragma unroll
      for (int q = 0; q < 4; q++) {
        float g = bf2f(hrow[ch + j + q]);
        float u = bf2f(hrow[64 + ch + j + q]);
        float s = g / (1.f + __expf(-g));
        ((unsigned short*)&o)[q] = f2bf(s * u);
      }
      *(ushort4*)(orow + j) = o;
    }
  }
}

__global__ __launch_bounds__(256, 4) void k_gemm2b(const unsigned short* __restrict__ w2b,
    const unsigned short* __restrict__ act, float* __restrict__ out,
    const int* __restrict__ ctrl, const int* __restrict__ rtok,
    const float* __restrict__ rwgt) {
  struct __align__(16) Lds2 { unsigned char A[16384]; unsigned char B[16384]; };
  __shared__ Lds2 lds;
  int mt = blockIdx.y, ml;
  int e = tile_lookup(ctrl, mt, &ml);
  if (e < 0) return;
  int nt = blockIdx.x;                               // 0..7 : out cols [nt*128, +128)
  int tid = threadIdx.x, lane = tid & 63, wid = tid >> 6, wr = wid >> 1, wc = wid & 1;
  int rbase = ctrl[16 + e] + ml * 128;
  const unsigned char* Ab = (const unsigned char*)(act + (size_t)rbase * INTER);
  const unsigned char* Bb = (const unsigned char*)(w2b + (size_t)e * HIDDEN * INTER);
  int swz = ((lane & 7) ^ (lane >> 3)) << 4;
  int l3 = lane >> 3;

  f32x4 acc[4][4];
  f32x4 zero = {0.f, 0.f, 0.f, 0.f};
#pragma unroll
  for (int i = 0; i < 4; i++)
#pragma unroll
    for (int j = 0; j < 4; j++) acc[i][j] = zero;

  for (int kk = 0; kk < INTER / 64; ++kk) {
#pragma unroll
    for (int i = 0; i < 4; i++) {
      int g = wid * 4 + i;
      gload16(Ab + (size_t)(g * 8 + l3) * (INTER * 2) + kk * 128 + swz, &lds.A[g * 1024]);
    }
#pragma unroll
    for (int i = 0; i < 4; i++) {
      int g = wid * 4 + i;
      gload16(Bb + (size_t)(nt * 128 + g * 8 + l3) * (INTER * 2) + kk * 128 + swz, &lds.B[g * 1024]);
    }
    __syncthreads();
#pragma unroll
    for (int ks = 0; ks < 2; ++ks) {
      short8 a[4], b[4];
#pragma unroll
      for (int mi = 0; mi < 4; mi++) {
        int row = wr * 64 + mi * 16 + (lane & 15);
        int koff = ks * 64 + ((lane >> 4) << 4);
        a[mi] = *(const short8*)&lds.A[row * 128 + (koff ^ ((row & 7) << 4))];
      }
#pragma unroll
      for (int ni = 0; ni < 4; ni++) {
        int row = wc * 64 + ni * 16 + (lane & 15);
        int koff = ks * 64 + ((lane >> 4) << 4);
        b[ni] = *(const short8*)&lds.B[row * 128 + (koff ^ ((row & 7) << 4))];
      }
#pragma unroll
      for (int mi = 0; mi < 4; mi++)
#pragma unroll
        for (int ni = 0; ni < 4; ni++)
          acc[mi][ni] = __builtin_amdgcn_mfma_f32_16x16x32_bf16(a[mi], b[ni], acc[mi][ni], 0, 0, 0);
    }
    __syncthreads();
  }
  int cn = ctrl[e];
#pragma unroll
  for (int mi = 0; mi < 4; mi++)
#pragma unroll
    for (int ni = 0; ni < 4; ni++)
#pragma unroll
      for (int r = 0; r < 4; r++) {
        int rl = wr * 64 + mi * 16 + ((lane >> 4) << 2) + r;
        if (ml * 128 + rl < cn) {
          int rowg = rbase + rl;
          int t = rtok[rowg];
          float wgt = rwgt[rowg];
          int col = nt * 128 + wc * 64 + ni * 16 + (lane & 15);
          atomicAdd(out + (size_t)t * HIDDEN + col, wgt * acc[mi][ni][r]);
        }
      }
}

// ================= fallback path (R1): fp32 weights converted in-kernel ============
__global__ __launch_bounds__(256, 2) void k_gemm1(const float* __restrict__ w1,
    const unsigned short* __restrict__ Abf, unsigned short* __restrict__ act,
    const int* __restrict__ ctrl) {
  union __align__(16) LdsU {
    struct { unsigned char A[16384]; unsigned char B[16384]; } st;
    unsigned short hb[128 * 132];
  };
  __shared__ LdsU lds;
  int mt = blockIdx.y, ml;
  int e = tile_lookup(ctrl, mt, &ml);
  if (e < 0) return;
  int nt = blockIdx.x;
  int tid = threadIdx.x, lane = tid & 63, wid = tid >> 6, wr = wid >> 1, wc = wid & 1;
  int rbase = ctrl[16 + e] + ml * 128;
  const unsigned char* Ab = (const unsigned char*)(Abf + (size_t)rbase * HIDDEN);
  const float* Bb = w1 + (size_t)e * N1 * HIDDEN;
  f32x4 acc[4][4];
  f32x4 zero = {0.f, 0.f, 0.f, 0.f};
#pragma unroll
  for (int i = 0; i < 4; i++)
#pragma unroll
    for (int j = 0; j < 4; j++) acc[i][j] = zero;
  for (int kk = 0; kk < HIDDEN / 64; ++kk) {
#pragma unroll
    for (int i = 0; i < 4; i++) {
      int g = wid * 4 + i;
      gload16(Ab + (size_t)(g * 8 + (lane >> 3)) * (HIDDEN * 2) + kk * 128 + (((lane & 7) ^ (lane >> 3)) << 4),
              &lds.st.A[g * 1024]);
    }
#pragma unroll
    for (int i = 0; i < 8; i++) {
      int f = i * 256 + tid;
      int row = f >> 4, kq = f & 15;
      int grow = (row < 64) ? (nt * 64 + row) : (INTER + nt * 64 + (row - 64));
      float4 v = *(const float4*)(Bb + (size_t)grow * HIDDEN + kk * 64 + kq * 4);
      ushort4 o; o.x = f2bf(v.x); o.y = f2bf(v.y); o.z = f2bf(v.z); o.w = f2bf(v.w);
      *(ushort4*)&lds.st.B[row * 128 + ((kq * 8) ^ ((row & 7) << 4))] = o;
    }
    __syncthreads();
#pragma unroll
    for (int ks = 0; ks < 2; ++ks) {
      short8 a[4], b[4];
#pragma unroll
      for (int mi = 0; mi < 4; mi++) {
        int row = wr * 64 + mi * 16 + (lane & 15);
        int koff = ks * 64 + ((lane >> 4) << 4);
        a[mi] = *(const short8*)&lds.st.A[row * 128 + (koff ^ ((row & 7) << 4))];
      }
#pragma unroll
      for (int ni = 0; ni < 4; ni++) {
        int row = wc * 64 + ni * 16 + (lane & 15);
        int koff = ks * 64 + ((lane >> 4) << 4);
        b[ni] = *(const short8*)&lds.st.B[row * 128 + (koff ^ ((row & 7) << 4))];
      }
#pragma unroll
      for (int mi = 0; mi < 4; mi++)
#pragma unroll
        for (int ni = 0; ni < 4; ni++)
          acc[mi][ni] = __builtin_amdgcn_mfma_f32_16x16x32_bf16(a[mi], b[ni], acc[mi][ni], 0, 0, 0);
    }
    __syncthreads();
  }
#pragma unroll
  for (int mi = 0; mi < 4; mi++)
#pragma unroll
    for (int ni = 0; ni < 4; ni++)
#pragma unroll
      for (int r = 0; r < 4; r++) {
        int row = wr * 64 + mi * 16 + ((lane >> 4) << 2) + r;
        int col = wc * 64 + ni * 16 + (lane & 15);
        lds.hb[row * 132 + col] = f2bf(acc[mi][ni][r]);
      }
  __syncthreads();
  {
    int r = tid >> 1, ch = (tid & 1) * 32;
    unsigned short* orow = act + (size_t)(rbase + r) * INTER + nt * 64 + ch;
    const unsigned short* hrow = &lds.hb[r * 132];
#pragma unroll
    for (int j = 0; j < 32; j += 4) {
      ushort4 o;
#pragma unroll
      for (int q = 0; q < 4; q++) {
        float g = bf2f(hrow[ch + j + q]);
        float u = bf2f(hrow[64 + ch + j + q]);
        float s = g / (1.f + __expf(-g));
        ((unsigned short*)&o)[q] = f2bf(s * u);
      }
      *(ushort4*)(orow + j) = o;
    }
  }
}

__global__ __launch_bounds__(256, 2) void k_gemm2(const float* __restrict__ w2,
    const unsigned short* __restrict__ act, float* __restrict__ out,
    const int* __restrict__ ctrl, const int* __restrict__ rtok,
    const float* __restrict__ rwgt) {
  struct __align__(16) Lds2 { unsigned char A[16384]; unsigned char B[16384]; };
  __shared__ Lds2 lds;
  int mt = blockIdx.y, ml;
  int e = tile_lookup(ctrl, mt, &ml);
  if (e < 0) return;
  int nt = blockIdx.x;
  int tid = threadIdx.x, lane = tid & 63, wid = tid >> 6, wr = wid >> 1, wc = wid & 1;
  int rbase = ctrl[16 + e] + ml * 128;
  const unsigned char* Ab = (const unsigned char*)(act + (size_t)rbase * INTER);
  const float* Bb = w2 + (size_t)e * HIDDEN * INTER + (size_t)(nt * 128) * INTER;
  f32x4 acc[4][4];
  f32x4 zero = {0.f, 0.f, 0.f, 0.f};
#pragma unroll
  for (int i = 0; i < 4; i++)
#pragma unroll
    for (int j = 0; j < 4; j++) acc[i][j] = zero;
  for (int kk = 0; kk < INTER / 64; ++kk) {
#pragma unroll
    for (int i = 0; i < 4; i++) {
      int g = wid * 4 + i;
      gload16(Ab + (size_t)(g * 8 + (lane >> 3)) * (INTER * 2) + kk * 128 + (((lane & 7) ^ (lane >> 3)) << 4),
              &lds.A[g * 1024]);
    }
#pragma unroll
    for (int i = 0; i < 8; i++) {
      int f = i * 256 + tid;
      int row = f >> 4, kq = f & 15;
      float4 v = *(const float4*)(Bb + (size_t)row * INTER + kk * 64 + kq * 4);
      ushort4 o; o.x = f2bf(v.x); o.y = f2bf(v.y); o.z = f2bf(v.z); o.w = f2bf(v.w);
      *(ushort4*)&lds.B[row * 128 + ((kq * 8) ^ ((row & 7) << 4))] = o;
    }
    __syncthreads();
#pragma unroll
    for (int ks = 0; ks < 2; ++ks) {
      short8 a[4], b[4];
#pragma unroll
      for (int mi = 0; mi < 4; mi++) {
        int row = wr * 64 + mi * 16 + (lane & 15);
        int koff = ks * 64 + ((lane >> 4) << 4);
        a[mi] = *(const short8*)&lds.A[row * 128 + (koff ^ ((row & 7) << 4))];
      }
#pragma unroll
      for (int ni = 0; ni < 4; ni++) {
        int row = wc * 64 + ni * 16 + (lane & 15);
        int koff = ks * 64 + ((lane >> 4) << 4);
        b[ni] = *(const short8*)&lds.B[row * 128 + (koff ^ ((row & 7) << 4))];
      }
#pragma unroll
      for (int mi = 0; mi < 4; mi++)
#pragma unroll
        for (int ni = 0; ni < 4; ni++)
          acc[mi][ni] = __builtin_amdgcn_mfma_f32_16x16x32_bf16(a[mi], b[ni], acc[mi][ni], 0, 0, 0);
    }
    __syncthreads();
  }
  int cn = ctrl[e];
#pragma unroll
  for (int mi = 0; mi < 4; mi++)
#pragma unroll
    for (int ni = 0; ni < 4; ni++)
#pragma unroll
      for (int r = 0; r < 4; r++) {
        int rl = wr * 64 + mi * 16 + ((lane >> 4) << 2) + r;
        if (ml * 128 + rl < cn) {
          int rowg = rbase + rl;
          int t = rtok[rowg];
          float wgt = rwgt[rowg];
          int col = nt * 128 + wc * 64 + ni * 16 + (lane & 15);
          atomicAdd(out + (size_t)t * HIDDEN + col, wgt * acc[mi][ni][r]);
        }
      }
}

extern "C" void kernel_launch(void* const* d_in, const int* in_sizes, int n_in,
                              void* d_out, int out_size, void* d_ws, size_t ws_size,
                              hipStream_t stream) {
  const float* x      = (const float*)d_in[0];
  const float* gating = (const float*)d_in[1];
  const float* w1     = (const float*)d_in[2];
  const float* w2     = (const float*)d_in[3];
  float* out = (float*)d_out;
  char* ws = (char*)d_ws;

  // ws layout
  int*   ctrl = (int*)ws;                                   // cnt[8] cursor[8] base[8]
  int*   tkid = (int*)(ws + 1024);
  float* tkw  = (float*)(ws + 17408);
  int*   rtok = (int*)(ws + 33792);
  float* rwgt = (float*)(ws + 54272);
  size_t off_Abf = 131072;
  size_t off_act = off_Abf + (size_t)ROWCAP * HIDDEN * 2;          // +10.49 MB
  size_t off_w1b = off_act + (size_t)ROWCAP * INTER * 2;           // +28.84 MB
  size_t off_w2b = off_w1b + (size_t)NEXP * N1 * HIDDEN * 2;       // +92.27 MB
  size_t need    = off_w2b + (size_t)NEXP * HIDDEN * INTER * 2;    // 177.9 MB total
  unsigned short* Abf  = (unsigned short*)(ws + off_Abf);
  unsigned short* actb = (unsigned short*)(ws + off_act);
  unsigned short* w1b  = (unsigned short*)(ws + off_w1b);
  unsigned short* w2b  = (unsigned short*)(ws + off_w2b);

  hipMemsetAsync(d_out, 0, (size_t)TOKENS * HIDDEN * sizeof(float), stream);
  hipMemsetAsync(ws, 0, 1024, stream);

  bool fast = (ws_size >= need);
  if (fast) {
    k_conv<<<2048, 256, 0, stream>>>(w1, w1b, NEXP * N1 * HIDDEN / 8);
    k_conv<<<2048, 256, 0, stream>>>(w2, w2b, NEXP * HIDDEN * INTER / 8);
  }
  k_routing<<<TOKENS / 256, 256, 0, stream>>>(gating, ctrl, tkid, tkw);
  k_base<<<1, 64, 0, stream>>>(ctrl);
  k_fill<<<TOKENS / 256, 256, 0, stream>>>(ctrl, tkid, tkw, rtok, rwgt);
  k_gather<<<ROWCAP, 256, 0, stream>>>(x, ctrl, rtok, Abf);
  if (fast) {
    k_gemm1b<<<dim3(N1 / 128, 40), 256, 0, stream>>>(w1b, Abf, actb, ctrl);
    k_gemm2b<<<dim3(HIDDEN / 128, 40), 256, 0, stream>>>(w2b, actb, out, ctrl, rtok, rwgt);
  } else {
    k_gemm1<<<dim3(N1 / 128, 40), 256, 0, stream>>>(w1, Abf, actb, ctrl);
    k_gemm2<<<dim3(HIDDEN / 128, 40), 256, 0, stream>>>(w2, actb, out, ctrl, rtok, rwgt);
  }
}

// Round 3
// 243.264 us; speedup vs baseline: 1.3228x; 1.1814x over previous
//
#include <hip/hip_runtime.h>
#include <hip/hip_bf16.h>

#define TOKENS 2048
#define HIDDEN 1024
#define NEXP   8
#define INTER  2816
#define N1     5632   // 2*INTER
#define ROWCAP 5120   // 4096 pairs + 8*128 padding worst case
#define SPLITK 2      // gemm2 K-slices

typedef __attribute__((ext_vector_type(8))) short short8;   // 8 bf16 = 4 VGPR (MFMA A/B frag)
typedef __attribute__((ext_vector_type(4))) float f32x4;    // MFMA C/D frag

typedef unsigned int __attribute__((address_space(1))) as1_uint;
typedef unsigned int __attribute__((address_space(3))) as3_uint;

__device__ __forceinline__ void gload16(const void* g, void* l) {
  // async global->LDS, 16B/lane, LDS dest = wave-uniform base + lane*16
  __builtin_amdgcn_global_load_lds((const as1_uint*)g, (as3_uint*)l, 16, 0, 0);
}

__device__ __forceinline__ unsigned short f2bf(float f) {  // RNE f32->bf16 (bit trick)
  unsigned u = __float_as_uint(f);
  u += 0x7fff + ((u >> 16) & 1);
  return (unsigned short)(u >> 16);
}
__device__ __forceinline__ float bf2f(unsigned short h) {
  return __uint_as_float(((unsigned)h) << 16);
}
__device__ __forceinline__ unsigned short bfs(float x) {   // compiler-lowered cvt (fuses to v_cvt_pk_bf16_f32)
  __hip_bfloat16 h = __float2bfloat16(x);
  return *reinterpret_cast<unsigned short*>(&h);
}
__device__ __forceinline__ short8 pack8(f32x4 lo, f32x4 hi) {
  short8 o;
  o[0] = (short)bfs(lo[0]); o[1] = (short)bfs(lo[1]); o[2] = (short)bfs(lo[2]); o[3] = (short)bfs(lo[3]);
  o[4] = (short)bfs(hi[0]); o[5] = (short)bfs(hi[1]); o[6] = (short)bfs(hi[2]); o[7] = (short)bfs(hi[3]);
  return o;
}

// ---------------- routing: softmax->top2->renorm == sigmoid(l0-l1) ----------------
__global__ void k_routing(const float* __restrict__ gate, int* __restrict__ ctrl,
                          int* __restrict__ tkid, float* __restrict__ tkw) {
  int t = blockIdx.x * blockDim.x + threadIdx.x;
  if (t >= TOKENS) return;
  float l[8];
#pragma unroll
  for (int i = 0; i < 8; i++) l[i] = gate[t * 8 + i];
  int i0 = 0; float m0 = l[0];
#pragma unroll
  for (int i = 1; i < 8; i++) if (l[i] > m0) { m0 = l[i]; i0 = i; }
  int i1 = -1; float m1 = -3.4e38f;
#pragma unroll
  for (int i = 0; i < 8; i++) if (i != i0 && l[i] > m1) { m1 = l[i]; i1 = i; }
  float e  = __expf(m1 - m0);          // <= 1, stable
  float w0 = 1.f / (1.f + e);
  float w1 = e / (1.f + e);
  tkid[2 * t] = i0; tkid[2 * t + 1] = i1;
  tkw[2 * t] = w0;  tkw[2 * t + 1] = w1;
  atomicAdd(&ctrl[i0], 1);
  atomicAdd(&ctrl[i1], 1);
}

// ctrl layout (ints): [0..7]=cnt  [8..15]=cursor  [16..23]=base (128-aligned prefix)
__global__ void k_base(int* ctrl) {
  if (threadIdx.x == 0) {
    int a = 0;
    for (int e = 0; e < 8; e++) { ctrl[16 + e] = a; a += ((ctrl[e] + 127) >> 7) << 7; }
  }
}

__global__ void k_fill(int* __restrict__ ctrl, const int* __restrict__ tkid,
                       int* __restrict__ rtok, int* __restrict__ trow) {
  int t = blockIdx.x * blockDim.x + threadIdx.x;
  if (t >= TOKENS) return;
#pragma unroll
  for (int k = 0; k < 2; k++) {
    int e = tkid[2 * t + k];
    int pos = atomicAdd(&ctrl[8 + e], 1);
    int row = ctrl[16 + e] + pos;
    rtok[row] = t;
    trow[2 * t + k] = row;
  }
}

// gather x rows (f32) -> bf16 A matrix ordered by expert segment; zero padded rows
__global__ void k_gather(const float* __restrict__ x, const int* __restrict__ ctrl,
                         const int* __restrict__ rtok, unsigned short* __restrict__ Abf) {
  int row = blockIdx.x;
  int e = -1, local = 0;
  for (int i = 0; i < 8; i++) {
    int b = ctrl[16 + i], p = ((ctrl[i] + 127) >> 7) << 7;
    if (row >= b && row < b + p) { e = i; local = row - b; break; }
  }
  if (e < 0) return;
  int tid = threadIdx.x;
  unsigned short* dst = Abf + (size_t)row * HIDDEN;
  if (local < ctrl[e]) {
    int t = rtok[row];
    float4 v = ((const float4*)(x + (size_t)t * HIDDEN))[tid];
    ushort4 o; o.x = f2bf(v.x); o.y = f2bf(v.y); o.z = f2bf(v.z); o.w = f2bf(v.w);
    ((ushort4*)dst)[tid] = o;
  } else {
    ushort4 z; z.x = 0; z.y = 0; z.z = 0; z.w = 0;
    ((ushort4*)dst)[tid] = z;
  }
}

// expert/tile lookup shared by all GEMMs
__device__ __forceinline__ int tile_lookup(const int* ctrl, int mt, int* ml) {
  int a0 = 0;
  for (int i = 0; i < 8; i++) {
    int pt = (ctrl[i] + 127) >> 7;
    if (mt < a0 + pt) { *ml = mt - a0; return i; }
    a0 += pt;
  }
  return -1;
}

// ============ GEMM1: h = A(bf16) * w1[e](f32,->bf16 post-LDS)^T, fused SiLU ============
// A: [128][64] bf16 LDS (16KB), B: [128][64] f32 LDS (32KB). Both staged via
// global_load_lds with pre-swizzled source; XOR-swizzle on 16B blocks within row.
__global__ __launch_bounds__(256, 3) void k_gemm1(const float* __restrict__ w1,
    const unsigned short* __restrict__ Abf, unsigned short* __restrict__ act,
    const int* __restrict__ ctrl) {
  union __align__(16) LdsU {
    struct { unsigned char A[16384]; unsigned char B[32768]; } st;
    unsigned short hb[128 * 132];
  };
  __shared__ LdsU lds;
  int mt = blockIdx.y, ml;
  int e = tile_lookup(ctrl, mt, &ml);
  if (e < 0) return;
  int nt = blockIdx.x;                               // 0..43 : inter cols [nt*64, nt*64+64)
  int tid = threadIdx.x, lane = tid & 63, wid = tid >> 6, wr = wid >> 1, wc = wid & 1;
  int rbase = ctrl[16 + e] + ml * 128;
  const unsigned char* Ab = (const unsigned char*)(Abf + (size_t)rbase * HIDDEN);
  const unsigned char* Bb = (const unsigned char*)(w1 + (size_t)e * N1 * HIDDEN);
  int swzA = ((lane & 7) ^ (lane >> 3)) << 4;        // A: 8 rows/instr, 8x16B blocks/row
  int l3 = lane >> 3;
  int l4 = lane >> 4;                                 // B: 4 rows/instr, 16x16B blocks/row

  f32x4 acc[4][4];
  f32x4 zero = {0.f, 0.f, 0.f, 0.f};
#pragma unroll
  for (int i = 0; i < 4; i++)
#pragma unroll
    for (int j = 0; j < 4; j++) acc[i][j] = zero;

  for (int kk = 0; kk < HIDDEN / 64; ++kk) {
#pragma unroll
    for (int i = 0; i < 4; i++) {
      int g = wid * 4 + i;                           // 16 groups of 8 A-rows
      gload16(Ab + (size_t)(g * 8 + l3) * (HIDDEN * 2) + kk * 128 + swzA, &lds.st.A[g * 1024]);
    }
#pragma unroll
    for (int i = 0; i < 8; i++) {
      int g = wid * 8 + i;                           // 32 groups of 4 B-rows (f32)
      int r = g * 4 + l4;                            // 0..127
      int grow = (r < 64) ? (nt * 64 + r) : (INTER + nt * 64 + r - 64);
      int jsrc = ((lane & 15) ^ (r & 7)) << 4;
      gload16(Bb + (size_t)grow * (HIDDEN * 4) + kk * 256 + jsrc, &lds.st.B[g * 1024]);
    }
    __syncthreads();
#pragma unroll
    for (int ks = 0; ks < 2; ++ks) {
      short8 a[4], b[4];
#pragma unroll
      for (int mi = 0; mi < 4; mi++) {
        int row = wr * 64 + mi * 16 + (lane & 15);
        int koff = ks * 64 + (l4 << 4);
        a[mi] = *(const short8*)&lds.st.A[row * 128 + (koff ^ ((row & 7) << 4))];
      }
#pragma unroll
      for (int ni = 0; ni < 4; ni++) {
        int r = wc * 64 + ni * 16 + (lane & 15);
        int b0 = ks * 8 + (l4 << 1);
        f32x4 lo = *(const f32x4*)&lds.st.B[r * 256 + ((b0 ^ (r & 7)) << 4)];
        f32x4 hi = *(const f32x4*)&lds.st.B[r * 256 + (((b0 + 1) ^ (r & 7)) << 4)];
        b[ni] = pack8(lo, hi);
      }
#pragma unroll
      for (int mi = 0; mi < 4; mi++)
#pragma unroll
        for (int ni = 0; ni < 4; ni++)
          acc[mi][ni] = __builtin_amdgcn_mfma_f32_16x16x32_bf16(a[mi], b[ni], acc[mi][ni], 0, 0, 0);
    }
    __syncthreads();
  }
  // epilogue: h -> LDS (bf16), then act = silu(gate)*up -> global
#pragma unroll
  for (int mi = 0; mi < 4; mi++)
#pragma unroll
    for (int ni = 0; ni < 4; ni++)
#pragma unroll
      for (int r = 0; r < 4; r++) {
        int row = wr * 64 + mi * 16 + ((lane >> 4) << 2) + r;   // C/D: row=(lane>>4)*4+reg
        int col = wc * 64 + ni * 16 + (lane & 15);              //      col=lane&15
        lds.hb[row * 132 + col] = f2bf(acc[mi][ni][r]);
      }
  __syncthreads();
  {
    int r = tid >> 1, ch = (tid & 1) * 32;
    unsigned short* orow = act + (size_t)(rbase + r) * INTER + nt * 64 + ch;
    const unsigned short* hrow = &lds.hb[r * 132];
#pragma unroll
    for (int j = 0; j < 32; j += 4) {
      ushort4 o;
#pragma unroll
      for (int q = 0; q < 4; q++) {
        float g = bf2f(hrow[ch + j + q]);
        float u = bf2f(hrow[64 + ch + j + q]);
        float s = g / (1.f + __expf(-g));
        ((unsigned short*)&o)[q] = f2bf(s * u);
      }
      *(ushort4*)(orow + j) = o;
    }
  }
}

// ============ GEMM2: P[z] = act * w2[e](f32)^T over K-slice z; plain f32 stores ============
__global__ __launch_bounds__(256, 3) void k_gemm2(const float* __restrict__ w2,
    const unsigned short* __restrict__ act, float* __restrict__ P0, float* __restrict__ P1,
    const int* __restrict__ ctrl) {
  struct __align__(16) Lds2 { unsigned char A[16384]; unsigned char B[32768]; };
  __shared__ Lds2 lds;
  int mt = blockIdx.y, ml;
  int e = tile_lookup(ctrl, mt, &ml);
  if (e < 0) return;
  int nt = blockIdx.x;                               // 0..7 : out cols [nt*128, +128)
  int z  = blockIdx.z;                               // K-slice
  int tid = threadIdx.x, lane = tid & 63, wid = tid >> 6, wr = wid >> 1, wc = wid & 1;
  int rbase = ctrl[16 + e] + ml * 128;
  const unsigned char* Ab = (const unsigned char*)(act + (size_t)rbase * INTER);
  const unsigned char* Bb = (const unsigned char*)(w2 + (size_t)e * HIDDEN * INTER);
  int swzA = ((lane & 7) ^ (lane >> 3)) << 4;
  int l3 = lane >> 3, l4 = lane >> 4;
  const int KST = (INTER / 64) / SPLITK;             // 22 k-steps per slice

  f32x4 acc[4][4];
  f32x4 zero = {0.f, 0.f, 0.f, 0.f};
#pragma unroll
  for (int i = 0; i < 4; i++)
#pragma unroll
    for (int j = 0; j < 4; j++) acc[i][j] = zero;

  for (int s = 0; s < KST; ++s) {
    int kk = z * KST + s;
#pragma unroll
    for (int i = 0; i < 4; i++) {
      int g = wid * 4 + i;
      gload16(Ab + (size_t)(g * 8 + l3) * (INTER * 2) + kk * 128 + swzA, &lds.A[g * 1024]);
    }
#pragma unroll
    for (int i = 0; i < 8; i++) {
      int g = wid * 8 + i;
      int r = g * 4 + l4;
      int jsrc = ((lane & 15) ^ (r & 7)) << 4;
      gload16(Bb + (size_t)(nt * 128 + r) * (INTER * 4) + kk * 256 + jsrc, &lds.B[g * 1024]);
    }
    __syncthreads();
#pragma unroll
    for (int ks = 0; ks < 2; ++ks) {
      short8 a[4], b[4];
#pragma unroll
      for (int mi = 0; mi < 4; mi++) {
        int row = wr * 64 + mi * 16 + (lane & 15);
        int koff = ks * 64 + (l4 << 4);
        a[mi] = *(const short8*)&lds.A[row * 128 + (koff ^ ((row & 7) << 4))];
      }
#pragma unroll
      for (int ni = 0; ni < 4; ni++) {
        int r = wc * 64 + ni * 16 + (lane & 15);
        int b0 = ks * 8 + (l4 << 1);
        f32x4 lo = *(const f32x4*)&lds.B[r * 256 + ((b0 ^ (r & 7)) << 4)];
        f32x4 hi = *(const f32x4*)&lds.B[r * 256 + (((b0 + 1) ^ (r & 7)) << 4)];
        b[ni] = pack8(lo, hi);
      }
#pragma unroll
      for (int mi = 0; mi < 4; mi++)
#pragma unroll
        for (int ni = 0; ni < 4; ni++)
          acc[mi][ni] = __builtin_amdgcn_mfma_f32_16x16x32_bf16(a[mi], b[ni], acc[mi][ni], 0, 0, 0);
    }
    __syncthreads();
  }
  // plain f32 stores into slice buffer (deterministic; padded rows hold zeros)
  float* P = z ? P1 : P0;
#pragma unroll
  for (int mi = 0; mi < 4; mi++)
#pragma unroll
    for (int ni = 0; ni < 4; ni++) {
      int col = nt * 128 + wc * 64 + ni * 16 + (lane & 15);
#pragma unroll
      for (int r = 0; r < 4; r++) {
        int row = rbase + wr * 64 + mi * 16 + ((lane >> 4) << 2) + r;
        P[(size_t)row * HIDDEN + col] = acc[mi][ni][r];
      }
    }
}

// ---------------- final: out[t] = w0*(P0+P1)[row0] + w1*(P0+P1)[row1] ----------------
__global__ void k_finish(const float* __restrict__ P0, const float* __restrict__ P1,
                         const int* __restrict__ trow, const float* __restrict__ tkw,
                         float* __restrict__ out) {
  int t = blockIdx.x, c = threadIdx.x;
  int r0 = trow[2 * t], r1 = trow[2 * t + 1];
  float w0 = tkw[2 * t], w1 = tkw[2 * t + 1];
  float4 a0 = ((const float4*)(P0 + (size_t)r0 * HIDDEN))[c];
  float4 b0 = ((const float4*)(P1 + (size_t)r0 * HIDDEN))[c];
  float4 a1 = ((const float4*)(P0 + (size_t)r1 * HIDDEN))[c];
  float4 b1 = ((const float4*)(P1 + (size_t)r1 * HIDDEN))[c];
  float4 o;
  o.x = w0 * (a0.x + b0.x) + w1 * (a1.x + b1.x);
  o.y = w0 * (a0.y + b0.y) + w1 * (a1.y + b1.y);
  o.z = w0 * (a0.z + b0.z) + w1 * (a1.z + b1.z);
  o.w = w0 * (a0.w + b0.w) + w1 * (a1.w + b1.w);
  ((float4*)(out + (size_t)t * HIDDEN))[c] = o;
}

extern "C" void kernel_launch(void* const* d_in, const int* in_sizes, int n_in,
                              void* d_out, int out_size, void* d_ws, size_t ws_size,
                              hipStream_t stream) {
  const float* x      = (const float*)d_in[0];
  const float* gating = (const float*)d_in[1];
  const float* w1     = (const float*)d_in[2];
  const float* w2     = (const float*)d_in[3];
  float* out = (float*)d_out;
  char* ws = (char*)d_ws;

  // ws layout (total ~81.4 MB; R2 confirmed ws_size >= 178 MB)
  int*   ctrl = (int*)ws;                                   // cnt[8] cursor[8] base[8]
  int*   tkid = (int*)(ws + 1024);                          // 4096 ints
  float* tkw  = (float*)(ws + 17408);                       // 4096 floats
  int*   rtok = (int*)(ws + 33792);                         // 5120 ints
  int*   trow = (int*)(ws + 54272);                         // 4096 ints
  size_t off_Abf = 131072;
  size_t off_act = off_Abf + (size_t)ROWCAP * HIDDEN * 2;   // +10.49 MB
  size_t off_P0  = off_act + (size_t)ROWCAP * INTER * 2;    // +28.84 MB
  size_t off_P1  = off_P0  + (size_t)ROWCAP * HIDDEN * 4;   // +20.97 MB
  unsigned short* Abf  = (unsigned short*)(ws + off_Abf);
  unsigned short* actb = (unsigned short*)(ws + off_act);
  float* P0 = (float*)(ws + off_P0);
  float* P1 = (float*)(ws + off_P1);

  hipMemsetAsync(ws, 0, 1024, stream);

  k_routing<<<TOKENS / 256, 256, 0, stream>>>(gating, ctrl, tkid, tkw);
  k_base<<<1, 64, 0, stream>>>(ctrl);
  k_fill<<<TOKENS / 256, 256, 0, stream>>>(ctrl, tkid, rtok, trow);
  k_gather<<<ROWCAP, 256, 0, stream>>>(x, ctrl, rtok, Abf);
  k_gemm1<<<dim3(N1 / 128, 40), 256, 0, stream>>>(w1, Abf, actb, ctrl);
  k_gemm2<<<dim3(HIDDEN / 128, 40, SPLITK), 256, 0, stream>>>(w2, actb, P0, P1, ctrl);
  k_finish<<<TOKENS, 256, 0, stream>>>(P0, P1, trow, tkw, out);
}